// Round 1
// 623.405 us; speedup vs baseline: 1.0182x; 1.0182x over previous
//
#include <hip/hip_runtime.h>

typedef __bf16 bf16_t;
typedef bf16_t bf16x4 __attribute__((ext_vector_type(4)));
typedef bf16_t bf16x8 __attribute__((ext_vector_type(8)));
typedef float floatx4 __attribute__((ext_vector_type(4)));

#define EPSF 1e-5f
#define DEV static __device__ __forceinline__

// ---------------------------------------------------------------------------
// K0: swizzle weight matrices (f32 [K][128]) into B-fragment order, bf16.
// sw[((t*nK + s)*64 + l)*8 + j] = W[(s*32 + (l>>4)*8 + j)*128 + (t*16 + (l&15))]
// Layout ranges (bf16 elems): W_in@0(16384), W_ctx1@16384(32768),
// W_ctx2@49152(16384), W_m1@65536(16384), W_m2@81920(16384). Total 98304.
// ---------------------------------------------------------------------------
__global__ __launch_bounds__(256) void k_prep(
    const float* __restrict__ W_in, const float* __restrict__ W_ctx1,
    const float* __restrict__ W_ctx2, const float* __restrict__ W_m1,
    const float* __restrict__ W_m2, bf16_t* __restrict__ sw)
{
    int idx = blockIdx.x * 256 + threadIdx.x;   // grid sized to exactly 98304
    const float* W; int base, ks;
    if (idx < 16384)      { W = W_in;   base = 0;     ks = 2; }
    else if (idx < 49152) { W = W_ctx1; base = 16384; ks = 3; }
    else if (idx < 65536) { W = W_ctx2; base = 49152; ks = 2; }
    else if (idx < 81920) { W = W_m1;   base = 65536; ks = 2; }
    else                  { W = W_m2;   base = 81920; ks = 2; }
    int local = idx - base;
    int j = local & 7, l = (local >> 3) & 63, rest = local >> 9;
    int s = rest & ((1 << ks) - 1), t = rest >> ks;
    int k = s * 32 + (l >> 4) * 8 + j;
    int n = t * 16 + (l & 15);
    sw[idx] = (bf16_t)W[k * 128 + n];
}

// GroupNorm over 128 channels per row, operating on MFMA C-layout accumulators.
// acc[t][rr] holds element (row = (lane>>4)*4+rr, col = t*16 + (lane&15)).
DEV void gn_rows(floatx4* acc, int lane, const float* __restrict__ gamma,
                 const float* __restrict__ beta, bool do_relu)
{
    int m = lane & 15;
    float s1[4] = {0.f,0.f,0.f,0.f}, s2[4] = {0.f,0.f,0.f,0.f};
#pragma unroll
    for (int t = 0; t < 8; ++t)
#pragma unroll
        for (int rr = 0; rr < 4; ++rr) { float v = acc[t][rr]; s1[rr] += v; s2[rr] += v*v; }
#pragma unroll
    for (int mask = 1; mask <= 8; mask <<= 1)
#pragma unroll
        for (int rr = 0; rr < 4; ++rr) {
            s1[rr] += __shfl_xor(s1[rr], mask);
            s2[rr] += __shfl_xor(s2[rr], mask);
        }
    float mean[4], inv[4];
#pragma unroll
    for (int rr = 0; rr < 4; ++rr) {
        mean[rr] = s1[rr] * (1.f/128.f);
        float var = s2[rr] * (1.f/128.f) - mean[rr]*mean[rr];
        inv[rr] = rsqrtf(var + EPSF);
    }
#pragma unroll
    for (int t = 0; t < 8; ++t) {
        int n = t*16 + m;
        float ga = gamma[n], be = beta[n];
#pragma unroll
        for (int rr = 0; rr < 4; ++rr) {
            float v = (acc[t][rr] - mean[rr]) * inv[rr] * ga + be;
            acc[t][rr] = do_relu ? fmaxf(v, 0.f) : v;
        }
    }
}

// ---------------------------------------------------------------------------
// Binning: histogram of wi, exclusive scan -> off[Nt+1].
// ---------------------------------------------------------------------------
__global__ __launch_bounds__(256) void k_count(const int* __restrict__ wi,
                                               int* __restrict__ cnt, int E)
{
    int e = blockIdx.x * 256 + threadIdx.x;
    if (e < E) atomicAdd(&cnt[wi[e]], 1);
}

__global__ __launch_bounds__(1024) void k_scan(const int* __restrict__ cnt,
                                               int* __restrict__ off, int Nt)
{
    __shared__ int wsum[16];
    __shared__ int s_carry;
    int tid = threadIdx.x, lane = tid & 63, wid = tid >> 6;
    if (tid == 0) s_carry = 0;
    __syncthreads();
    for (int bs = 0; bs < Nt; bs += 4096) {
        int i0 = bs + tid * 4;
        int v0 = 0, v1 = 0, v2 = 0, v3 = 0;
        if (i0 + 3 < Nt) {
            int4 v = *(const int4*)(cnt + i0);
            v0 = v.x; v1 = v.y; v2 = v.z; v3 = v.w;
        } else {
            if (i0     < Nt) v0 = cnt[i0];
            if (i0 + 1 < Nt) v1 = cnt[i0+1];
            if (i0 + 2 < Nt) v2 = cnt[i0+2];
            if (i0 + 3 < Nt) v3 = cnt[i0+3];
        }
        int tot = v0 + v1 + v2 + v3;
        int x = tot;
#pragma unroll
        for (int d = 1; d < 64; d <<= 1) {
            int y = __shfl_up(x, d);
            if (lane >= d) x += y;
        }
        if (lane == 63) wsum[wid] = x;
        __syncthreads();
        if (wid == 0) {
            int wv = (lane < 16) ? wsum[lane] : 0;
#pragma unroll
            for (int d = 1; d < 16; d <<= 1) {
                int y = __shfl_up(wv, d);
                if (lane >= d) wv += y;
            }
            if (lane < 16) wsum[lane] = wv;
        }
        __syncthreads();
        int ebase = s_carry + ((wid > 0) ? wsum[wid-1] : 0) + (x - tot);
        if (i0 + 3 < Nt) {
            *(int4*)(off + i0) = make_int4(ebase, ebase+v0, ebase+v0+v1, ebase+v0+v1+v2);
        } else {
            if (i0     < Nt) off[i0]   = ebase;
            if (i0 + 1 < Nt) off[i0+1] = ebase + v0;
            if (i0 + 2 < Nt) off[i0+2] = ebase + v0 + v1;
            if (i0 + 3 < Nt) off[i0+3] = ebase + v0 + v1 + v2;
        }
        __syncthreads();
        if (tid == 0) s_carry += wsum[15];
        __syncthreads();
    }
    if (tid == 0) off[Nt] = s_carry;
}

// ---------------------------------------------------------------------------
// K2 (new): per-edge h = relu(GN(cat @ W_ctx1)); write h row (bf16) into its
// target's bin slot. ONE atomic per edge (slot claim) instead of 128 f32
// atomics. No W_ctx2 GEMM here (moved to k_out2 via linearity).
// ---------------------------------------------------------------------------
__global__ __launch_bounds__(256) void k_edge2(
    const float* __restrict__ cfeat, const float* __restrict__ cpose,
    const float* __restrict__ tpose, const int* __restrict__ hi,
    const int* __restrict__ wi, const float* __restrict__ W_rp,
    const float* __restrict__ b_rp, const float* __restrict__ g_ctx,
    const float* __restrict__ be_ctx, const bf16_t* __restrict__ swC1,
    const int* __restrict__ off, int* __restrict__ cur,
    bf16_t* __restrict__ hbuf, int E)
{
    __shared__ alignas(16) bf16_t sA[4][4096];    // per-wave [16 x 256] A-frag order
    int tid = threadIdx.x, lane = tid & 63, wave = tid >> 6;

    int tb = (blockIdx.x * 4 + wave) * 16;
    int r = lane >> 2, c = lane & 3, cb = c * 32;
    int e = min(tb + r, E - 1);
    bool ev = (tb + r) < E;
    int ci = hi[e], ti = wi[e];
    // context features -> k in [0,128)
    const float4* src = (const float4*)(cfeat + (size_t)ci * 128 + cb);
#pragma unroll
    for (int i = 0; i < 8; ++i) {
        float4 v = src[i];
        int k = cb + 4*i;
        int s = k >> 5, q = (k >> 3) & 3, j = k & 7;
        bf16x4 pk = { (bf16_t)v.x, (bf16_t)v.y, (bf16_t)v.z, (bf16_t)v.w };
        *(bf16x4*)&sA[wave][(s*64 + q*16 + r)*8 + j] = pk;
    }
    // relpose MLP -> k in [128,256)
    float4 cp = ((const float4*)cpose)[ci];
    float4 tp = ((const float4*)tpose)[ti];
    float d0 = cp.x - tp.x, d1 = cp.y - tp.y, d2 = cp.z - tp.z, d3 = cp.w - tp.w;
#pragma unroll
    for (int i = 0; i < 8; ++i) {
        int cc = cb + 4*i;
        float4 w0 = *(const float4*)(W_rp + cc);
        float4 w1 = *(const float4*)(W_rp + 128 + cc);
        float4 w2 = *(const float4*)(W_rp + 256 + cc);
        float4 w3 = *(const float4*)(W_rp + 384 + cc);
        float4 bb = *(const float4*)(b_rp + cc);
        float o0 = fmaxf(d0*w0.x + d1*w1.x + d2*w2.x + d3*w3.x + bb.x, 0.f);
        float o1 = fmaxf(d0*w0.y + d1*w1.y + d2*w2.y + d3*w3.y + bb.y, 0.f);
        float o2 = fmaxf(d0*w0.z + d1*w1.z + d2*w2.z + d3*w3.z + bb.z, 0.f);
        float o3 = fmaxf(d0*w0.w + d1*w1.w + d2*w2.w + d3*w3.w + bb.w, 0.f);
        int k = 128 + cc;
        int s = k >> 5, q = (k >> 3) & 3, j = k & 7;
        bf16x4 pk = { (bf16_t)o0, (bf16_t)o1, (bf16_t)o2, (bf16_t)o3 };
        *(bf16x4*)&sA[wave][(s*64 + q*16 + r)*8 + j] = pk;
    }
    __syncthreads();

    int m = lane & 15, g = lane >> 4;
    bf16x8 aF[8];
#pragma unroll
    for (int s = 0; s < 8; ++s) aF[s] = *(const bf16x8*)&sA[wave][(s*64 + lane)*8];
    floatx4 acc[8];
#pragma unroll
    for (int t = 0; t < 8; ++t) {
        floatx4 a = {0.f,0.f,0.f,0.f};
#pragma unroll
        for (int s = 0; s < 8; ++s) {
            bf16x8 bF = *(const bf16x8*)&swC1[(size_t)((t*8+s)*64 + lane)*8];
            a = __builtin_amdgcn_mfma_f32_16x16x32_bf16(aF[s], bF, a, 0, 0, 0);
        }
        acc[t] = a;
    }
    gn_rows(acc, lane, g_ctx, be_ctx, true);

    // restage h rows into sA[wave] as [16][136] bf16 (same-wave LDS: in-order,
    // frags already consumed; pad 8 elems/row to spread banks).
#pragma unroll
    for (int t = 0; t < 8; ++t)
#pragma unroll
        for (int rr = 0; rr < 4; ++rr)
            sA[wave][(g*4+rr)*136 + t*16 + m] = (bf16_t)acc[t][rr];

    // claim slot (one atomic per edge), broadcast to the 4 lanes of the row
    int dst = 0;
    if (ev && c == 0) dst = off[ti] + atomicAdd(&cur[ti], 1);
    dst = __shfl(dst, lane & ~3);
    if (ev) {
        bf16_t* hp = hbuf + (size_t)dst * 128 + cb;
#pragma unroll
        for (int i = 0; i < 4; ++i)
            *(bf16x8*)(hp + i*8) = *(const bf16x8*)&sA[wave][r*136 + cb + i*8];
    }
}

// ---------------------------------------------------------------------------
// K3 (new): per 16 target rows:
//   tf = tfeat@W_in + (sum of binned h rows)@W_ctx2      (one fused MFMA chain)
//   out = relu(GN(relu(GN(relu(GN(tf)) @ W_m1)) @ W_m2) + tfeat)
// h gather is CONTIGUOUS (bins sorted by target). Epilogue store is float4-
// coalesced via LDS transpose.
// ---------------------------------------------------------------------------
__global__ __launch_bounds__(256) void k_out2(
    const float* __restrict__ tfeat, const bf16_t* __restrict__ hbuf,
    const int* __restrict__ off,
    const float* __restrict__ g_n, const float* __restrict__ be_n,
    const float* __restrict__ g_m1, const float* __restrict__ be_m1,
    const float* __restrict__ g_m2, const float* __restrict__ be_m2,
    const bf16_t* __restrict__ swIn, const bf16_t* __restrict__ swC2,
    const bf16_t* __restrict__ swM1, const bf16_t* __restrict__ swM2,
    float* __restrict__ out, int Nt)
{
    __shared__ alignas(16) bf16_t sA[4][4096];  // per-wave 8KB: [0,2048) tfeat frag, [2048,4096) Hsum frag
    int tid = threadIdx.x, lane = tid & 63, wave = tid >> 6;
    int tb = (blockIdx.x*4 + wave)*16;
    int r = lane >> 2, c = lane & 3, cb = c*32;
    int grow = tb + r;
    bool rv = grow < Nt;

    // stage tfeat -> region1 (A-frag, K=128)
    const float4* src = (const float4*)(tfeat + (size_t)(rv ? grow : 0)*128 + cb);
#pragma unroll
    for (int i = 0; i < 8; ++i) {
        float4 v = rv ? src[i] : make_float4(0.f,0.f,0.f,0.f);
        int k = cb + 4*i;
        int s = k >> 5, q = (k >> 3) & 3, j = k & 7;
        bf16x4 pk = { (bf16_t)v.x, (bf16_t)v.y, (bf16_t)v.z, (bf16_t)v.w };
        *(bf16x4*)&sA[wave][(s*64 + q*16 + r)*8 + j] = pk;
    }
    // gather-sum this row's h bin (contiguous rows [off[grow], off[grow+1]))
    float sums[32];
#pragma unroll
    for (int i = 0; i < 32; ++i) sums[i] = 0.f;
    int jb = rv ? off[grow] : 0, je = rv ? off[grow+1] : 0;
    for (int jr = jb; jr < je; ++jr) {
        const bf16x8* hp = (const bf16x8*)(hbuf + (size_t)jr*128 + cb);
#pragma unroll
        for (int i = 0; i < 4; ++i) {
            bf16x8 hv = hp[i];
#pragma unroll
            for (int q = 0; q < 8; ++q) sums[i*8+q] += (float)hv[q];
        }
    }
    // pack Hsum -> region2 (A-frag, K=128)
#pragma unroll
    for (int i = 0; i < 8; ++i) {
        int k = cb + 4*i;
        int s = k >> 5, q = (k >> 3) & 3, j = k & 7;
        bf16x4 pk = { (bf16_t)sums[4*i], (bf16_t)sums[4*i+1],
                      (bf16_t)sums[4*i+2], (bf16_t)sums[4*i+3] };
        *(bf16x4*)&sA[wave][2048 + (s*64 + q*16 + r)*8 + j] = pk;
    }
    __syncthreads();
    int m = lane & 15, g = lane >> 4;
    bf16x8 aF[4], aH[4];
#pragma unroll
    for (int s = 0; s < 4; ++s) {
        aF[s] = *(const bf16x8*)&sA[wave][(s*64 + lane)*8];
        aH[s] = *(const bf16x8*)&sA[wave][2048 + (s*64 + lane)*8];
    }
    floatx4 acc[8];
#pragma unroll
    for (int t = 0; t < 8; ++t) {
        floatx4 a = {0.f,0.f,0.f,0.f};
#pragma unroll
        for (int s = 0; s < 4; ++s)
            a = __builtin_amdgcn_mfma_f32_16x16x32_bf16(aF[s],
                  *(const bf16x8*)&swIn[((t*4+s)*64 + lane)*8], a, 0, 0, 0);
#pragma unroll
        for (int s = 0; s < 4; ++s)
            a = __builtin_amdgcn_mfma_f32_16x16x32_bf16(aH[s],
                  *(const bf16x8*)&swC2[((t*4+s)*64 + lane)*8], a, 0, 0, 0);
        acc[t] = a;
    }
    gn_rows(acc, lane, g_n, be_n, true);
    __syncthreads();
#pragma unroll
    for (int t = 0; t < 8; ++t) {
        int n = t*16 + m;
        int s = n >> 5, q = (n >> 3) & 3, j = n & 7;
#pragma unroll
        for (int rr = 0; rr < 4; ++rr)
            sA[wave][(s*64 + q*16 + (g*4+rr))*8 + j] = (bf16_t)acc[t][rr];
    }
    __syncthreads();
#pragma unroll
    for (int s = 0; s < 4; ++s) aF[s] = *(const bf16x8*)&sA[wave][(s*64 + lane)*8];
#pragma unroll
    for (int t = 0; t < 8; ++t) {
        floatx4 a = {0.f,0.f,0.f,0.f};
#pragma unroll
        for (int s = 0; s < 4; ++s)
            a = __builtin_amdgcn_mfma_f32_16x16x32_bf16(aF[s],
                  *(const bf16x8*)&swM1[((t*4+s)*64 + lane)*8], a, 0, 0, 0);
        acc[t] = a;
    }
    gn_rows(acc, lane, g_m1, be_m1, true);
    __syncthreads();
#pragma unroll
    for (int t = 0; t < 8; ++t) {
        int n = t*16 + m;
        int s = n >> 5, q = (n >> 3) & 3, j = n & 7;
#pragma unroll
        for (int rr = 0; rr < 4; ++rr)
            sA[wave][(s*64 + q*16 + (g*4+rr))*8 + j] = (bf16_t)acc[t][rr];
    }
    __syncthreads();
#pragma unroll
    for (int s = 0; s < 4; ++s) aF[s] = *(const bf16x8*)&sA[wave][(s*64 + lane)*8];
#pragma unroll
    for (int t = 0; t < 8; ++t) {
        floatx4 a = {0.f,0.f,0.f,0.f};
#pragma unroll
        for (int s = 0; s < 4; ++s)
            a = __builtin_amdgcn_mfma_f32_16x16x32_bf16(aF[s],
                  *(const bf16x8*)&swM2[((t*4+s)*64 + lane)*8], a, 0, 0, 0);
        acc[t] = a;
    }
    gn_rows(acc, lane, g_m2, be_m2, false);

    // transpose via LDS (f32, reuse whole 8KB) -> coalesced float4 epilogue
    __syncthreads();
    float* sF = (float*)&sA[wave][0];
#pragma unroll
    for (int t = 0; t < 8; ++t)
#pragma unroll
        for (int rr = 0; rr < 4; ++rr)
            sF[(g*4+rr)*128 + t*16 + m] = acc[t][rr];
    __syncthreads();
    const float4* idp = (const float4*)(tfeat + (size_t)tb*128);
    float4* op = (float4*)(out + (size_t)tb*128);
    const float4* sf4 = (const float4*)sF;
    int maxf = (Nt - tb < 16) ? (Nt - tb) * 32 : 512;
#pragma unroll
    for (int kk = 0; kk < 8; ++kk) {
        int f = kk*64 + lane;
        if (f < maxf) {
            float4 v = sf4[f], idv = idp[f];
            v.x = fmaxf(v.x + idv.x, 0.f);
            v.y = fmaxf(v.y + idv.y, 0.f);
            v.z = fmaxf(v.z + idv.z, 0.f);
            v.w = fmaxf(v.w + idv.w, 0.f);
            op[f] = v;
        }
    }
}

// ===========================================================================
// FALLBACK PATH (previous kernels, used only if workspace is too small for
// the binned h buffer).
// ===========================================================================
__global__ __launch_bounds__(256) void k_gemm_in(
    const float* __restrict__ tfeat, const bf16_t* __restrict__ swW,
    float* __restrict__ tf, int Nt)
{
    __shared__ alignas(16) bf16_t sA[4][2048];
    int tid = threadIdx.x, lane = tid & 63, wave = tid >> 6;

    int tb = (blockIdx.x * 4 + wave) * 16;
    int r = lane >> 2, cb = (lane & 3) * 32;
    int grow = tb + r;
    bool rv = grow < Nt;
    const float4* src = (const float4*)(tfeat + (size_t)(rv ? grow : 0) * 128 + cb);
#pragma unroll
    for (int i = 0; i < 8; ++i) {
        float4 v = rv ? src[i] : make_float4(0.f,0.f,0.f,0.f);
        int k = cb + 4*i;
        int s = k >> 5, q = (k >> 3) & 3, j = k & 7;
        bf16x4 pk = { (bf16_t)v.x, (bf16_t)v.y, (bf16_t)v.z, (bf16_t)v.w };
        *(bf16x4*)&sA[wave][(s*64 + q*16 + r)*8 + j] = pk;
    }
    __syncthreads();
    int m = lane & 15, g = lane >> 4;
    bf16x8 aF[4];
#pragma unroll
    for (int s = 0; s < 4; ++s) aF[s] = *(const bf16x8*)&sA[wave][(s*64 + lane)*8];
#pragma unroll
    for (int t = 0; t < 8; ++t) {
        floatx4 a = {0.f,0.f,0.f,0.f};
#pragma unroll
        for (int s = 0; s < 4; ++s) {
            bf16x8 bF = *(const bf16x8*)&swW[((t*4+s)*64 + lane)*8];
            a = __builtin_amdgcn_mfma_f32_16x16x32_bf16(aF[s], bF, a, 0, 0, 0);
        }
#pragma unroll
        for (int rr = 0; rr < 4; ++rr) {
            int row = tb + g*4 + rr;
            if (row < Nt) tf[(size_t)row*128 + t*16 + m] = a[rr];
        }
    }
}

__global__ __launch_bounds__(256) void k_edge_old(
    const float* __restrict__ cfeat, const float* __restrict__ cpose,
    const float* __restrict__ tpose, const int* __restrict__ hi,
    const int* __restrict__ wi, const float* __restrict__ W_rp,
    const float* __restrict__ b_rp, const float* __restrict__ g_ctx,
    const float* __restrict__ be_ctx, const bf16_t* __restrict__ swC1,
    const bf16_t* __restrict__ swC2, float* __restrict__ tf, int E)
{
    __shared__ alignas(16) bf16_t sA[4][4096];
    int tid = threadIdx.x, lane = tid & 63, wave = tid >> 6;

    int tb = (blockIdx.x * 4 + wave) * 16;
    int r = lane >> 2, cb = (lane & 3) * 32;
    int e = min(tb + r, E - 1);
    int ci = hi[e], ti = wi[e];
    const float4* src = (const float4*)(cfeat + (size_t)ci * 128 + cb);
#pragma unroll
    for (int i = 0; i < 8; ++i) {
        float4 v = src[i];
        int k = cb + 4*i;
        int s = k >> 5, q = (k >> 3) & 3, j = k & 7;
        bf16x4 pk = { (bf16_t)v.x, (bf16_t)v.y, (bf16_t)v.z, (bf16_t)v.w };
        *(bf16x4*)&sA[wave][(s*64 + q*16 + r)*8 + j] = pk;
    }
    float4 cp = ((const float4*)cpose)[ci];
    float4 tp = ((const float4*)tpose)[ti];
    float d0 = cp.x - tp.x, d1 = cp.y - tp.y, d2 = cp.z - tp.z, d3 = cp.w - tp.w;
#pragma unroll
    for (int i = 0; i < 8; ++i) {
        int cc = cb + 4*i;
        float4 w0 = *(const float4*)(W_rp + cc);
        float4 w1 = *(const float4*)(W_rp + 128 + cc);
        float4 w2 = *(const float4*)(W_rp + 256 + cc);
        float4 w3 = *(const float4*)(W_rp + 384 + cc);
        float4 bb = *(const float4*)(b_rp + cc);
        float o0 = fmaxf(d0*w0.x + d1*w1.x + d2*w2.x + d3*w3.x + bb.x, 0.f);
        float o1 = fmaxf(d0*w0.y + d1*w1.y + d2*w2.y + d3*w3.y + bb.y, 0.f);
        float o2 = fmaxf(d0*w0.z + d1*w1.z + d2*w2.z + d3*w3.z + bb.z, 0.f);
        float o3 = fmaxf(d0*w0.w + d1*w1.w + d2*w2.w + d3*w3.w + bb.w, 0.f);
        int k = 128 + cc;
        int s = k >> 5, q = (k >> 3) & 3, j = k & 7;
        bf16x4 pk = { (bf16_t)o0, (bf16_t)o1, (bf16_t)o2, (bf16_t)o3 };
        *(bf16x4*)&sA[wave][(s*64 + q*16 + r)*8 + j] = pk;
    }
    __syncthreads();

    int m = lane & 15, g = lane >> 4;
    bf16x8 aF[8];
#pragma unroll
    for (int s = 0; s < 8; ++s) aF[s] = *(const bf16x8*)&sA[wave][(s*64 + lane)*8];
    floatx4 acc[8];
#pragma unroll
    for (int t = 0; t < 8; ++t) {
        floatx4 a = {0.f,0.f,0.f,0.f};
#pragma unroll
        for (int s = 0; s < 8; ++s) {
            bf16x8 bF = *(const bf16x8*)&swC1[(size_t)((t*8+s)*64 + lane)*8];
            a = __builtin_amdgcn_mfma_f32_16x16x32_bf16(aF[s], bF, a, 0, 0, 0);
        }
        acc[t] = a;
    }
    gn_rows(acc, lane, g_ctx, be_ctx, true);
    __syncthreads();
#pragma unroll
    for (int t = 0; t < 8; ++t) {
        int n = t*16 + m;
        int s = n >> 5, q = (n >> 3) & 3, j = n & 7;
#pragma unroll
        for (int rr = 0; rr < 4; ++rr)
            sA[wave][(s*64 + q*16 + (g*4+rr))*8 + j] = (bf16_t)acc[t][rr];
    }
    __syncthreads();
    bf16x8 aF2[4];
#pragma unroll
    for (int s = 0; s < 4; ++s) aF2[s] = *(const bf16x8*)&sA[wave][(s*64 + lane)*8];
    int dstrow[4]; bool vald[4];
#pragma unroll
    for (int rr = 0; rr < 4; ++rr) {
        int ee = tb + g*4 + rr;
        vald[rr] = ee < E;
        dstrow[rr] = vald[rr] ? wi[ee] : 0;
    }
#pragma unroll
    for (int t = 0; t < 8; ++t) {
        floatx4 a = {0.f,0.f,0.f,0.f};
#pragma unroll
        for (int s = 0; s < 4; ++s) {
            bf16x8 bF = *(const bf16x8*)&swC2[((t*4+s)*64 + lane)*8];
            a = __builtin_amdgcn_mfma_f32_16x16x32_bf16(aF2[s], bF, a, 0, 0, 0);
        }
#pragma unroll
        for (int rr = 0; rr < 4; ++rr) {
            if (vald[rr])
                atomicAdd(&tf[(size_t)dstrow[rr]*128 + t*16 + m], a[rr]);
        }
    }
}

__global__ __launch_bounds__(256) void k_out_old(
    const float* __restrict__ tf, const float* __restrict__ identity,
    const float* __restrict__ g_n, const float* __restrict__ be_n,
    const float* __restrict__ g_m1, const float* __restrict__ be_m1,
    const float* __restrict__ g_m2, const float* __restrict__ be_m2,
    const bf16_t* __restrict__ swM1, const bf16_t* __restrict__ swM2,
    float* __restrict__ out, int Nt)
{
    __shared__ alignas(16) bf16_t sA[4][2048];
    int tid = threadIdx.x, lane = tid & 63, wave = tid >> 6;

    int tb = (blockIdx.x*4 + wave)*16;
    int r = lane >> 2, cb = (lane & 3)*32;
    int grow = tb + r;
    bool rv = grow < Nt;
    const float4* src = (const float4*)(tf + (size_t)(rv ? grow : 0)*128 + cb);
    float vals[32];
    float ls = 0.f, lq = 0.f;
#pragma unroll
    for (int i = 0; i < 8; ++i) {
        float4 v = rv ? src[i] : make_float4(0.f,0.f,0.f,0.f);
        vals[4*i+0]=v.x; vals[4*i+1]=v.y; vals[4*i+2]=v.z; vals[4*i+3]=v.w;
        ls += v.x+v.y+v.z+v.w;
        lq += v.x*v.x+v.y*v.y+v.z*v.z+v.w*v.w;
    }
    ls += __shfl_xor(ls,1); lq += __shfl_xor(lq,1);
    ls += __shfl_xor(ls,2); lq += __shfl_xor(lq,2);
    float mean = ls*(1.f/128.f);
    float inv = rsqrtf(lq*(1.f/128.f) - mean*mean + EPSF);
#pragma unroll
    for (int i = 0; i < 8; ++i) {
        int cc = cb + 4*i;
        float4 ga = *(const float4*)(g_n + cc);
        float4 be = *(const float4*)(be_n + cc);
        float o0 = fmaxf((vals[4*i+0]-mean)*inv*ga.x + be.x, 0.f);
        float o1 = fmaxf((vals[4*i+1]-mean)*inv*ga.y + be.y, 0.f);
        float o2 = fmaxf((vals[4*i+2]-mean)*inv*ga.z + be.z, 0.f);
        float o3 = fmaxf((vals[4*i+3]-mean)*inv*ga.w + be.w, 0.f);
        int s = cc >> 5, q = (cc >> 3) & 3, j = cc & 7;
        bf16x4 pk = { (bf16_t)o0, (bf16_t)o1, (bf16_t)o2, (bf16_t)o3 };
        *(bf16x4*)&sA[wave][(s*64 + q*16 + r)*8 + j] = pk;
    }
    __syncthreads();
    int m = lane & 15, g = lane >> 4;
    bf16x8 aF[4];
#pragma unroll
    for (int s = 0; s < 4; ++s) aF[s] = *(const bf16x8*)&sA[wave][(s*64 + lane)*8];
    floatx4 acc[8];
#pragma unroll
    for (int t = 0; t < 8; ++t) {
        floatx4 a = {0.f,0.f,0.f,0.f};
#pragma unroll
        for (int s = 0; s < 4; ++s) {
            bf16x8 bF = *(const bf16x8*)&swM1[((t*4+s)*64 + lane)*8];
            a = __builtin_amdgcn_mfma_f32_16x16x32_bf16(aF[s], bF, a, 0, 0, 0);
        }
        acc[t] = a;
    }
    gn_rows(acc, lane, g_m1, be_m1, true);
    __syncthreads();
#pragma unroll
    for (int t = 0; t < 8; ++t) {
        int n = t*16 + m;
        int s = n >> 5, q = (n >> 3) & 3, j = n & 7;
#pragma unroll
        for (int rr = 0; rr < 4; ++rr)
            sA[wave][(s*64 + q*16 + (g*4+rr))*8 + j] = (bf16_t)acc[t][rr];
    }
    __syncthreads();
#pragma unroll
    for (int s = 0; s < 4; ++s) aF[s] = *(const bf16x8*)&sA[wave][(s*64 + lane)*8];
#pragma unroll
    for (int t = 0; t < 8; ++t) {
        floatx4 a = {0.f,0.f,0.f,0.f};
#pragma unroll
        for (int s = 0; s < 4; ++s) {
            bf16x8 bF = *(const bf16x8*)&swM2[((t*4+s)*64 + lane)*8];
            a = __builtin_amdgcn_mfma_f32_16x16x32_bf16(aF[s], bF, a, 0, 0, 0);
        }
        acc[t] = a;
    }
    gn_rows(acc, lane, g_m2, be_m2, false);
#pragma unroll
    for (int t = 0; t < 8; ++t) {
        int n = t*16 + m;
#pragma unroll
        for (int rr = 0; rr < 4; ++rr) {
            int row = tb + g*4 + rr;
            if (row < Nt) {
                float v = acc[t][rr] + identity[(size_t)row*128 + n];
                out[(size_t)row*128 + n] = fmaxf(v, 0.f);
            }
        }
    }
}

// ---------------------------------------------------------------------------
extern "C" void kernel_launch(void* const* d_in, const int* in_sizes, int n_in,
                              void* d_out, int out_size, void* d_ws, size_t ws_size,
                              hipStream_t stream)
{
    const float* cfeat  = (const float*)d_in[0];
    const float* tfeat  = (const float*)d_in[1];
    const float* cpose  = (const float*)d_in[2];
    const float* tpose  = (const float*)d_in[3];
    const int*   hi     = (const int*)d_in[4];
    const int*   wi     = (const int*)d_in[5];
    const float* W_in   = (const float*)d_in[6];
    const float* W_rp   = (const float*)d_in[7];
    const float* b_rp   = (const float*)d_in[8];
    const float* W_ctx1 = (const float*)d_in[9];
    const float* g_ctx  = (const float*)d_in[10];
    const float* be_ctx = (const float*)d_in[11];
    const float* W_ctx2 = (const float*)d_in[12];
    const float* g_n    = (const float*)d_in[13];
    const float* be_n   = (const float*)d_in[14];
    const float* W_m1   = (const float*)d_in[15];
    const float* g_m1   = (const float*)d_in[16];
    const float* be_m1  = (const float*)d_in[17];
    const float* W_m2   = (const float*)d_in[18];
    const float* g_m2   = (const float*)d_in[19];
    const float* be_m2  = (const float*)d_in[20];

    int Nt = in_sizes[1] / 128;
    int E  = in_sizes[4];
    float* outp = (float*)d_out;

    // new-path workspace layout
    char* base = (char*)d_ws;
    size_t o = 98304 * sizeof(bf16_t);                 // sw @ 0
    o = (o + 255) & ~(size_t)255;
    size_t o_cnt = o; o += (size_t)Nt * 4;
    o = (o + 255) & ~(size_t)255;
    size_t o_off = o; o += ((size_t)Nt + 1) * 4;
    o = (o + 255) & ~(size_t)255;
    size_t o_cur = o; o += (size_t)Nt * 4;
    o = (o + 255) & ~(size_t)255;
    size_t o_h = o; o += (size_t)E * 128 * sizeof(bf16_t);

    if (ws_size >= o) {
        bf16_t* sw   = (bf16_t*)base;
        int*    cnt  = (int*)(base + o_cnt);
        int*    off  = (int*)(base + o_off);
        int*    cur  = (int*)(base + o_cur);
        bf16_t* hbuf = (bf16_t*)(base + o_h);
        bf16_t* swIn = sw;
        bf16_t* swC1 = sw + 16384;
        bf16_t* swC2 = sw + 49152;
        bf16_t* swM1 = sw + 65536;
        bf16_t* swM2 = sw + 81920;

        hipMemsetAsync(cnt, 0, (size_t)Nt * 4, stream);
        hipMemsetAsync(cur, 0, (size_t)Nt * 4, stream);
        k_prep<<<384, 256, 0, stream>>>(W_in, W_ctx1, W_ctx2, W_m1, W_m2, sw);
        k_count<<<(E + 255) / 256, 256, 0, stream>>>(wi, cnt, E);
        k_scan<<<1, 1024, 0, stream>>>(cnt, off, Nt);
        k_edge2<<<(E + 63) / 64, 256, 0, stream>>>(cfeat, cpose, tpose, hi, wi,
                                                   W_rp, b_rp, g_ctx, be_ctx,
                                                   swC1, off, cur, hbuf, E);
        k_out2<<<(Nt + 63) / 64, 256, 0, stream>>>(tfeat, hbuf, off,
                                                   g_n, be_n, g_m1, be_m1,
                                                   g_m2, be_m2,
                                                   swIn, swC2, swM1, swM2,
                                                   outp, Nt);
    } else {
        // fallback: previous atomic-scatter path
        float*  tf = (float*)d_ws;                                   // [Nt,128] f32
        bf16_t* sw = (bf16_t*)((char*)d_ws + (size_t)Nt * 128 * sizeof(float));
        bf16_t* swIn = sw;
        bf16_t* swC1 = sw + 16384;
        bf16_t* swC2 = sw + 49152;
        bf16_t* swM1 = sw + 65536;
        bf16_t* swM2 = sw + 81920;

        k_prep<<<384, 256, 0, stream>>>(W_in, W_ctx1, W_ctx2, W_m1, W_m2, sw);
        k_gemm_in<<<(Nt + 63) / 64, 256, 0, stream>>>(tfeat, swIn, tf, Nt);
        k_edge_old<<<(E + 63) / 64, 256, 0, stream>>>(cfeat, cpose, tpose, hi, wi,
                                                      W_rp, b_rp, g_ctx, be_ctx,
                                                      swC1, swC2, tf, E);
        k_out_old<<<(Nt + 63) / 64, 256, 0, stream>>>(tf, tfeat, g_n, be_n,
                                                      g_m1, be_m1, g_m2, be_m2,
                                                      swM1, swM2, outp, Nt);
    }
}

// Round 2
// 506.336 us; speedup vs baseline: 1.2536x; 1.2312x over previous
//
#include <hip/hip_runtime.h>

typedef __bf16 bf16_t;
typedef bf16_t bf16x4 __attribute__((ext_vector_type(4)));
typedef bf16_t bf16x8 __attribute__((ext_vector_type(8)));
typedef float floatx4 __attribute__((ext_vector_type(4)));

#define EPSF 1e-5f
#define DEV static __device__ __forceinline__

// ---------------------------------------------------------------------------
// K0: swizzle weight matrices (f32 [K][128]) into B-fragment order, bf16.
// sw[((t*nK + s)*64 + l)*8 + j] = W[(s*32 + (l>>4)*8 + j)*128 + (t*16 + (l&15))]
// Layout ranges (bf16 elems): W_in@0(16384), W_ctx1@16384(32768),
// W_ctx2@49152(16384), W_m1@65536(16384), W_m2@81920(16384). Total 98304.
// ---------------------------------------------------------------------------
__global__ __launch_bounds__(256) void k_prep(
    const float* __restrict__ W_in, const float* __restrict__ W_ctx1,
    const float* __restrict__ W_ctx2, const float* __restrict__ W_m1,
    const float* __restrict__ W_m2, bf16_t* __restrict__ sw)
{
    int idx = blockIdx.x * 256 + threadIdx.x;   // grid sized to exactly 98304
    const float* W; int base, ks;
    if (idx < 16384)      { W = W_in;   base = 0;     ks = 2; }
    else if (idx < 49152) { W = W_ctx1; base = 16384; ks = 3; }
    else if (idx < 65536) { W = W_ctx2; base = 49152; ks = 2; }
    else if (idx < 81920) { W = W_m1;   base = 65536; ks = 2; }
    else                  { W = W_m2;   base = 81920; ks = 2; }
    int local = idx - base;
    int j = local & 7, l = (local >> 3) & 63, rest = local >> 9;
    int s = rest & ((1 << ks) - 1), t = rest >> ks;
    int k = s * 32 + (l >> 4) * 8 + j;
    int n = t * 16 + (l & 15);
    sw[idx] = (bf16_t)W[k * 128 + n];
}

// GroupNorm over 128 channels per row, operating on MFMA C-layout accumulators.
// acc[t][rr] holds element (row = (lane>>4)*4+rr, col = t*16 + (lane&15)).
DEV void gn_rows(floatx4* acc, int lane, const float* __restrict__ gamma,
                 const float* __restrict__ beta, bool do_relu)
{
    int m = lane & 15;
    float s1[4] = {0.f,0.f,0.f,0.f}, s2[4] = {0.f,0.f,0.f,0.f};
#pragma unroll
    for (int t = 0; t < 8; ++t)
#pragma unroll
        for (int rr = 0; rr < 4; ++rr) { float v = acc[t][rr]; s1[rr] += v; s2[rr] += v*v; }
#pragma unroll
    for (int mask = 1; mask <= 8; mask <<= 1)
#pragma unroll
        for (int rr = 0; rr < 4; ++rr) {
            s1[rr] += __shfl_xor(s1[rr], mask);
            s2[rr] += __shfl_xor(s2[rr], mask);
        }
    float mean[4], inv[4];
#pragma unroll
    for (int rr = 0; rr < 4; ++rr) {
        mean[rr] = s1[rr] * (1.f/128.f);
        float var = s2[rr] * (1.f/128.f) - mean[rr]*mean[rr];
        inv[rr] = rsqrtf(var + EPSF);
    }
#pragma unroll
    for (int t = 0; t < 8; ++t) {
        int n = t*16 + m;
        float ga = gamma[n], be = beta[n];
#pragma unroll
        for (int rr = 0; rr < 4; ++rr) {
            float v = (acc[t][rr] - mean[rr]) * inv[rr] * ga + be;
            acc[t][rr] = do_relu ? fmaxf(v, 0.f) : v;
        }
    }
}

// ---------------------------------------------------------------------------
// Binning: histogram of wi, exclusive scan -> off[Nt+1].
// ---------------------------------------------------------------------------
__global__ __launch_bounds__(256) void k_count(const int* __restrict__ wi,
                                               int* __restrict__ cnt, int E)
{
    int e = blockIdx.x * 256 + threadIdx.x;
    if (e < E) atomicAdd(&cnt[wi[e]], 1);
}

__global__ __launch_bounds__(1024) void k_scan(const int* __restrict__ cnt,
                                               int* __restrict__ off, int Nt)
{
    __shared__ int wsum[16];
    __shared__ int s_carry;
    int tid = threadIdx.x, lane = tid & 63, wid = tid >> 6;
    if (tid == 0) s_carry = 0;
    __syncthreads();
    for (int bs = 0; bs < Nt; bs += 4096) {
        int i0 = bs + tid * 4;
        int v0 = 0, v1 = 0, v2 = 0, v3 = 0;
        if (i0 + 3 < Nt) {
            int4 v = *(const int4*)(cnt + i0);
            v0 = v.x; v1 = v.y; v2 = v.z; v3 = v.w;
        } else {
            if (i0     < Nt) v0 = cnt[i0];
            if (i0 + 1 < Nt) v1 = cnt[i0+1];
            if (i0 + 2 < Nt) v2 = cnt[i0+2];
            if (i0 + 3 < Nt) v3 = cnt[i0+3];
        }
        int tot = v0 + v1 + v2 + v3;
        int x = tot;
#pragma unroll
        for (int d = 1; d < 64; d <<= 1) {
            int y = __shfl_up(x, d);
            if (lane >= d) x += y;
        }
        if (lane == 63) wsum[wid] = x;
        __syncthreads();
        if (wid == 0) {
            int wv = (lane < 16) ? wsum[lane] : 0;
#pragma unroll
            for (int d = 1; d < 16; d <<= 1) {
                int y = __shfl_up(wv, d);
                if (lane >= d) wv += y;
            }
            if (lane < 16) wsum[lane] = wv;
        }
        __syncthreads();
        int ebase = s_carry + ((wid > 0) ? wsum[wid-1] : 0) + (x - tot);
        if (i0 + 3 < Nt) {
            *(int4*)(off + i0) = make_int4(ebase, ebase+v0, ebase+v0+v1, ebase+v0+v1+v2);
        } else {
            if (i0     < Nt) off[i0]   = ebase;
            if (i0 + 1 < Nt) off[i0+1] = ebase + v0;
            if (i0 + 2 < Nt) off[i0+2] = ebase + v0 + v1;
            if (i0 + 3 < Nt) off[i0+3] = ebase + v0 + v1 + v2;
        }
        __syncthreads();
        if (tid == 0) s_carry += wsum[15];
        __syncthreads();
    }
    if (tid == 0) off[Nt] = s_carry;
}

// ---------------------------------------------------------------------------
// K2 (v3): barrier-free, direct-fragment gather.
// A-fragment for mfma_16x16x32: aF[s][j] = A[lane&15][s*32 + (lane>>4)*8 + j].
// Each lane gathers its own cfeat chunks and computes its own relpose outputs
// straight into fragment registers -- no A staging LDS, no __syncthreads.
// LDS only for the per-wave C-layout -> row-major restage of h ([16][136] pad).
// One slot-claim atomic per edge; h row written as 4x16B stores.
// ---------------------------------------------------------------------------
__global__ __launch_bounds__(256) void k_edge3(
    const float* __restrict__ cfeat, const float* __restrict__ cpose,
    const float* __restrict__ tpose, const int* __restrict__ hi,
    const int* __restrict__ wi, const float* __restrict__ W_rp,
    const float* __restrict__ b_rp, const float* __restrict__ g_ctx,
    const float* __restrict__ be_ctx, const bf16_t* __restrict__ swC1,
    const int* __restrict__ off, int* __restrict__ cur,
    bf16_t* __restrict__ hbuf, int E)
{
    __shared__ alignas(16) bf16_t sH[4][2176];   // per-wave [16][136] bf16, 17 KB/block
    int tid = threadIdx.x, lane = tid & 63, wave = tid >> 6;
    int tb = (blockIdx.x * 4 + wave) * 16;
    int r = lane & 15, g = lane >> 4;
    int e = min(tb + r, E - 1);
    int ci = hi[e], ti = wi[e];

    bf16x8 aF[8];
    // context features, k in [0,128): two float4 per s, in fragment order
    const float4* cf = (const float4*)(cfeat + (size_t)ci * 128);
#pragma unroll
    for (int s = 0; s < 4; ++s) {
        int f4 = s * 8 + g * 2;
        float4 v0 = cf[f4], v1 = cf[f4 + 1];
        aF[s] = (bf16x8){ (bf16_t)v0.x, (bf16_t)v0.y, (bf16_t)v0.z, (bf16_t)v0.w,
                          (bf16_t)v1.x, (bf16_t)v1.y, (bf16_t)v1.z, (bf16_t)v1.w };
    }
    // relpose MLP, k in [128,256): per-lane 4 chunks of 8 outputs
    float4 cp = ((const float4*)cpose)[ci];
    float4 tp = ((const float4*)tpose)[ti];
    float d0 = cp.x - tp.x, d1 = cp.y - tp.y, d2 = cp.z - tp.z, d3 = cp.w - tp.w;
#pragma unroll
    for (int sp = 0; sp < 4; ++sp) {
        int k0 = sp * 32 + g * 8;
        const float4* w0 = (const float4*)(W_rp + k0);
        const float4* w1 = (const float4*)(W_rp + 128 + k0);
        const float4* w2 = (const float4*)(W_rp + 256 + k0);
        const float4* w3 = (const float4*)(W_rp + 384 + k0);
        const float4* bb = (const float4*)(b_rp + k0);
        float o0,o1,o2,o3,o4,o5,o6,o7;
        {
            float4 a0=w0[0], a1=w1[0], a2=w2[0], a3=w3[0], ab=bb[0];
            o0 = fmaxf(d0*a0.x + d1*a1.x + d2*a2.x + d3*a3.x + ab.x, 0.f);
            o1 = fmaxf(d0*a0.y + d1*a1.y + d2*a2.y + d3*a3.y + ab.y, 0.f);
            o2 = fmaxf(d0*a0.z + d1*a1.z + d2*a2.z + d3*a3.z + ab.z, 0.f);
            o3 = fmaxf(d0*a0.w + d1*a1.w + d2*a2.w + d3*a3.w + ab.w, 0.f);
        }
        {
            float4 a0=w0[1], a1=w1[1], a2=w2[1], a3=w3[1], ab=bb[1];
            o4 = fmaxf(d0*a0.x + d1*a1.x + d2*a2.x + d3*a3.x + ab.x, 0.f);
            o5 = fmaxf(d0*a0.y + d1*a1.y + d2*a2.y + d3*a3.y + ab.y, 0.f);
            o6 = fmaxf(d0*a0.z + d1*a1.z + d2*a2.z + d3*a3.z + ab.z, 0.f);
            o7 = fmaxf(d0*a0.w + d1*a1.w + d2*a2.w + d3*a3.w + ab.w, 0.f);
        }
        aF[4 + sp] = (bf16x8){ (bf16_t)o0, (bf16_t)o1, (bf16_t)o2, (bf16_t)o3,
                               (bf16_t)o4, (bf16_t)o5, (bf16_t)o6, (bf16_t)o7 };
    }

    floatx4 acc[8];
#pragma unroll
    for (int t = 0; t < 8; ++t) {
        floatx4 a = {0.f,0.f,0.f,0.f};
#pragma unroll
        for (int s = 0; s < 8; ++s) {
            bf16x8 bF = *(const bf16x8*)&swC1[(size_t)((t*8 + s)*64 + lane)*8];
            a = __builtin_amdgcn_mfma_f32_16x16x32_bf16(aF[s], bF, a, 0, 0, 0);
        }
        acc[t] = a;
    }
    gn_rows(acc, lane, g_ctx, be_ctx, true);

    // restage h into per-wave LDS: row = g*4+rr, col = t*16 + r
#pragma unroll
    for (int t = 0; t < 8; ++t)
#pragma unroll
        for (int rr = 0; rr < 4; ++rr)
            sH[wave][(g*4 + rr)*136 + t*16 + r] = (bf16_t)acc[t][rr];

    // write-out: 4 lanes per row; one slot-claim atomic per edge
    int r2 = lane >> 2, c2 = lane & 3;
    bool ev2 = (tb + r2) < E;
    int ti2 = __shfl(ti, r2);          // lane r2 holds row r2's target
    int dst = 0;
    if (ev2 && c2 == 0) dst = off[ti2] + atomicAdd(&cur[ti2], 1);
    dst = __shfl(dst, lane & ~3);
    if (ev2) {
        bf16_t* hp = hbuf + (size_t)dst * 128 + c2 * 32;
#pragma unroll
        for (int i = 0; i < 4; ++i)
            *(bf16x8*)(hp + i*8) = *(const bf16x8*)&sH[wave][r2*136 + c2*32 + i*8];
    }
}

// ---------------------------------------------------------------------------
// K3: per 16 target rows:
//   tf = tfeat@W_in + (sum of binned h rows)@W_ctx2      (one fused MFMA chain)
//   out = relu(GN(relu(GN(relu(GN(tf)) @ W_m1)) @ W_m2) + tfeat)
// h gather is CONTIGUOUS (bins sorted by target). Epilogue store is float4-
// coalesced via LDS transpose.
// ---------------------------------------------------------------------------
__global__ __launch_bounds__(256) void k_out2(
    const float* __restrict__ tfeat, const bf16_t* __restrict__ hbuf,
    const int* __restrict__ off,
    const float* __restrict__ g_n, const float* __restrict__ be_n,
    const float* __restrict__ g_m1, const float* __restrict__ be_m1,
    const float* __restrict__ g_m2, const float* __restrict__ be_m2,
    const bf16_t* __restrict__ swIn, const bf16_t* __restrict__ swC2,
    const bf16_t* __restrict__ swM1, const bf16_t* __restrict__ swM2,
    float* __restrict__ out, int Nt)
{
    __shared__ alignas(16) bf16_t sA[4][4096];  // per-wave 8KB: [0,2048) tfeat frag, [2048,4096) Hsum frag
    int tid = threadIdx.x, lane = tid & 63, wave = tid >> 6;
    int tb = (blockIdx.x*4 + wave)*16;
    int r = lane >> 2, c = lane & 3, cb = c*32;
    int grow = tb + r;
    bool rv = grow < Nt;

    // stage tfeat -> region1 (A-frag, K=128)
    const float4* src = (const float4*)(tfeat + (size_t)(rv ? grow : 0)*128 + cb);
#pragma unroll
    for (int i = 0; i < 8; ++i) {
        float4 v = rv ? src[i] : make_float4(0.f,0.f,0.f,0.f);
        int k = cb + 4*i;
        int s = k >> 5, q = (k >> 3) & 3, j = k & 7;
        bf16x4 pk = { (bf16_t)v.x, (bf16_t)v.y, (bf16_t)v.z, (bf16_t)v.w };
        *(bf16x4*)&sA[wave][(s*64 + q*16 + r)*8 + j] = pk;
    }
    // gather-sum this row's h bin (contiguous rows [off[grow], off[grow+1]))
    float sums[32];
#pragma unroll
    for (int i = 0; i < 32; ++i) sums[i] = 0.f;
    int jb = rv ? off[grow] : 0, je = rv ? off[grow+1] : 0;
    for (int jr = jb; jr < je; ++jr) {
        const bf16x8* hp = (const bf16x8*)(hbuf + (size_t)jr*128 + cb);
#pragma unroll
        for (int i = 0; i < 4; ++i) {
            bf16x8 hv = hp[i];
#pragma unroll
            for (int q = 0; q < 8; ++q) sums[i*8+q] += (float)hv[q];
        }
    }
    // pack Hsum -> region2 (A-frag, K=128)
#pragma unroll
    for (int i = 0; i < 8; ++i) {
        int k = cb + 4*i;
        int s = k >> 5, q = (k >> 3) & 3, j = k & 7;
        bf16x4 pk = { (bf16_t)sums[4*i], (bf16_t)sums[4*i+1],
                      (bf16_t)sums[4*i+2], (bf16_t)sums[4*i+3] };
        *(bf16x4*)&sA[wave][2048 + (s*64 + q*16 + r)*8 + j] = pk;
    }
    __syncthreads();
    int m = lane & 15, g = lane >> 4;
    bf16x8 aF[4], aH[4];
#pragma unroll
    for (int s = 0; s < 4; ++s) {
        aF[s] = *(const bf16x8*)&sA[wave][(s*64 + lane)*8];
        aH[s] = *(const bf16x8*)&sA[wave][2048 + (s*64 + lane)*8];
    }
    floatx4 acc[8];
#pragma unroll
    for (int t = 0; t < 8; ++t) {
        floatx4 a = {0.f,0.f,0.f,0.f};
#pragma unroll
        for (int s = 0; s < 4; ++s)
            a = __builtin_amdgcn_mfma_f32_16x16x32_bf16(aF[s],
                  *(const bf16x8*)&swIn[((t*4+s)*64 + lane)*8], a, 0, 0, 0);
#pragma unroll
        for (int s = 0; s < 4; ++s)
            a = __builtin_amdgcn_mfma_f32_16x16x32_bf16(aH[s],
                  *(const bf16x8*)&swC2[((t*4+s)*64 + lane)*8], a, 0, 0, 0);
        acc[t] = a;
    }
    gn_rows(acc, lane, g_n, be_n, true);
    __syncthreads();
#pragma unroll
    for (int t = 0; t < 8; ++t) {
        int n = t*16 + m;
        int s = n >> 5, q = (n >> 3) & 3, j = n & 7;
#pragma unroll
        for (int rr = 0; rr < 4; ++rr)
            sA[wave][(s*64 + q*16 + (g*4+rr))*8 + j] = (bf16_t)acc[t][rr];
    }
    __syncthreads();
#pragma unroll
    for (int s = 0; s < 4; ++s) aF[s] = *(const bf16x8*)&sA[wave][(s*64 + lane)*8];
#pragma unroll
    for (int t = 0; t < 8; ++t) {
        floatx4 a = {0.f,0.f,0.f,0.f};
#pragma unroll
        for (int s = 0; s < 4; ++s)
            a = __builtin_amdgcn_mfma_f32_16x16x32_bf16(aF[s],
                  *(const bf16x8*)&swM1[((t*4+s)*64 + lane)*8], a, 0, 0, 0);
        acc[t] = a;
    }
    gn_rows(acc, lane, g_m1, be_m1, true);
    __syncthreads();
#pragma unroll
    for (int t = 0; t < 8; ++t) {
        int n = t*16 + m;
        int s = n >> 5, q = (n >> 3) & 3, j = n & 7;
#pragma unroll
        for (int rr = 0; rr < 4; ++rr)
            sA[wave][(s*64 + q*16 + (g*4+rr))*8 + j] = (bf16_t)acc[t][rr];
    }
    __syncthreads();
#pragma unroll
    for (int s = 0; s < 4; ++s) aF[s] = *(const bf16x8*)&sA[wave][(s*64 + lane)*8];
#pragma unroll
    for (int t = 0; t < 8; ++t) {
        floatx4 a = {0.f,0.f,0.f,0.f};
#pragma unroll
        for (int s = 0; s < 4; ++s)
            a = __builtin_amdgcn_mfma_f32_16x16x32_bf16(aF[s],
                  *(const bf16x8*)&swM2[((t*4+s)*64 + lane)*8], a, 0, 0, 0);
        acc[t] = a;
    }
    gn_rows(acc, lane, g_m2, be_m2, false);

    // transpose via LDS (f32, reuse whole 8KB) -> coalesced float4 epilogue
    __syncthreads();
    float* sF = (float*)&sA[wave][0];
#pragma unroll
    for (int t = 0; t < 8; ++t)
#pragma unroll
        for (int rr = 0; rr < 4; ++rr)
            sF[(g*4+rr)*128 + t*16 + m] = acc[t][rr];
    __syncthreads();
    const float4* idp = (const float4*)(tfeat + (size_t)tb*128);
    float4* op = (float4*)(out + (size_t)tb*128);
    const float4* sf4 = (const float4*)sF;
    int maxf = (Nt - tb < 16) ? (Nt - tb) * 32 : 512;
#pragma unroll
    for (int kk = 0; kk < 8; ++kk) {
        int f = kk*64 + lane;
        if (f < maxf) {
            float4 v = sf4[f], idv = idp[f];
            v.x = fmaxf(v.x + idv.x, 0.f);
            v.y = fmaxf(v.y + idv.y, 0.f);
            v.z = fmaxf(v.z + idv.z, 0.f);
            v.w = fmaxf(v.w + idv.w, 0.f);
            op[f] = v;
        }
    }
}

// ===========================================================================
// FALLBACK PATH (previous kernels, used only if workspace is too small for
// the binned h buffer).
// ===========================================================================
__global__ __launch_bounds__(256) void k_gemm_in(
    const float* __restrict__ tfeat, const bf16_t* __restrict__ swW,
    float* __restrict__ tf, int Nt)
{
    __shared__ alignas(16) bf16_t sA[4][2048];
    int tid = threadIdx.x, lane = tid & 63, wave = tid >> 6;

    int tb = (blockIdx.x * 4 + wave) * 16;
    int r = lane >> 2, cb = (lane & 3) * 32;
    int grow = tb + r;
    bool rv = grow < Nt;
    const float4* src = (const float4*)(tfeat + (size_t)(rv ? grow : 0) * 128 + cb);
#pragma unroll
    for (int i = 0; i < 8; ++i) {
        float4 v = rv ? src[i] : make_float4(0.f,0.f,0.f,0.f);
        int k = cb + 4*i;
        int s = k >> 5, q = (k >> 3) & 3, j = k & 7;
        bf16x4 pk = { (bf16_t)v.x, (bf16_t)v.y, (bf16_t)v.z, (bf16_t)v.w };
        *(bf16x4*)&sA[wave][(s*64 + q*16 + r)*8 + j] = pk;
    }
    __syncthreads();
    int m = lane & 15, g = lane >> 4;
    bf16x8 aF[4];
#pragma unroll
    for (int s = 0; s < 4; ++s) aF[s] = *(const bf16x8*)&sA[wave][(s*64 + lane)*8];
#pragma unroll
    for (int t = 0; t < 8; ++t) {
        floatx4 a = {0.f,0.f,0.f,0.f};
#pragma unroll
        for (int s = 0; s < 4; ++s) {
            bf16x8 bF = *(const bf16x8*)&swW[((t*4+s)*64 + lane)*8];
            a = __builtin_amdgcn_mfma_f32_16x16x32_bf16(aF[s], bF, a, 0, 0, 0);
        }
#pragma unroll
        for (int rr = 0; rr < 4; ++rr) {
            int row = tb + g*4 + rr;
            if (row < Nt) tf[(size_t)row*128 + t*16 + m] = a[rr];
        }
    }
}

__global__ __launch_bounds__(256) void k_edge_old(
    const float* __restrict__ cfeat, const float* __restrict__ cpose,
    const float* __restrict__ tpose, const int* __restrict__ hi,
    const int* __restrict__ wi, const float* __restrict__ W_rp,
    const float* __restrict__ b_rp, const float* __restrict__ g_ctx,
    const float* __restrict__ be_ctx, const bf16_t* __restrict__ swC1,
    const bf16_t* __restrict__ swC2, float* __restrict__ tf, int E)
{
    __shared__ alignas(16) bf16_t sA[4][4096];
    int tid = threadIdx.x, lane = tid & 63, wave = tid >> 6;

    int tb = (blockIdx.x * 4 + wave) * 16;
    int r = lane >> 2, cb = (lane & 3) * 32;
    int e = min(tb + r, E - 1);
    int ci = hi[e], ti = wi[e];
    const float4* src = (const float4*)(cfeat + (size_t)ci * 128 + cb);
#pragma unroll
    for (int i = 0; i < 8; ++i) {
        float4 v = src[i];
        int k = cb + 4*i;
        int s = k >> 5, q = (k >> 3) & 3, j = k & 7;
        bf16x4 pk = { (bf16_t)v.x, (bf16_t)v.y, (bf16_t)v.z, (bf16_t)v.w };
        *(bf16x4*)&sA[wave][(s*64 + q*16 + r)*8 + j] = pk;
    }
    float4 cp = ((const float4*)cpose)[ci];
    float4 tp = ((const float4*)tpose)[ti];
    float d0 = cp.x - tp.x, d1 = cp.y - tp.y, d2 = cp.z - tp.z, d3 = cp.w - tp.w;
#pragma unroll
    for (int i = 0; i < 8; ++i) {
        int cc = cb + 4*i;
        float4 w0 = *(const float4*)(W_rp + cc);
        float4 w1 = *(const float4*)(W_rp + 128 + cc);
        float4 w2 = *(const float4*)(W_rp + 256 + cc);
        float4 w3 = *(const float4*)(W_rp + 384 + cc);
        float4 bb = *(const float4*)(b_rp + cc);
        float o0 = fmaxf(d0*w0.x + d1*w1.x + d2*w2.x + d3*w3.x + bb.x, 0.f);
        float o1 = fmaxf(d0*w0.y + d1*w1.y + d2*w2.y + d3*w3.y + bb.y, 0.f);
        float o2 = fmaxf(d0*w0.z + d1*w1.z + d2*w2.z + d3*w3.z + bb.z, 0.f);
        float o3 = fmaxf(d0*w0.w + d1*w1.w + d2*w2.w + d3*w3.w + bb.w, 0.f);
        int k = 128 + cc;
        int s = k >> 5, q = (k >> 3) & 3, j = k & 7;
        bf16x4 pk = { (bf16_t)o0, (bf16_t)o1, (bf16_t)o2, (bf16_t)o3 };
        *(bf16x4*)&sA[wave][(s*64 + q*16 + r)*8 + j] = pk;
    }
    __syncthreads();

    int m = lane & 15, g = lane >> 4;
    bf16x8 aF[8];
#pragma unroll
    for (int s = 0; s < 8; ++s) aF[s] = *(const bf16x8*)&sA[wave][(s*64 + lane)*8];
    floatx4 acc[8];
#pragma unroll
    for (int t = 0; t < 8; ++t) {
        floatx4 a = {0.f,0.f,0.f,0.f};
#pragma unroll
        for (int s = 0; s < 8; ++s) {
            bf16x8 bF = *(const bf16x8*)&swC1[(size_t)((t*8+s)*64 + lane)*8];
            a = __builtin_amdgcn_mfma_f32_16x16x32_bf16(aF[s], bF, a, 0, 0, 0);
        }
        acc[t] = a;
    }
    gn_rows(acc, lane, g_ctx, be_ctx, true);
    __syncthreads();
#pragma unroll
    for (int t = 0; t < 8; ++t) {
        int n = t*16 + m;
        int s = n >> 5, q = (n >> 3) & 3, j = n & 7;
#pragma unroll
        for (int rr = 0; rr < 4; ++rr)
            sA[wave][(s*64 + q*16 + (g*4+rr))*8 + j] = (bf16_t)acc[t][rr];
    }
    __syncthreads();
    bf16x8 aF2[4];
#pragma unroll
    for (int s = 0; s < 4; ++s) aF2[s] = *(const bf16x8*)&sA[wave][(s*64 + lane)*8];
    int dstrow[4]; bool vald[4];
#pragma unroll
    for (int rr = 0; rr < 4; ++rr) {
        int ee = tb + g*4 + rr;
        vald[rr] = ee < E;
        dstrow[rr] = vald[rr] ? wi[ee] : 0;
    }
#pragma unroll
    for (int t = 0; t < 8; ++t) {
        floatx4 a = {0.f,0.f,0.f,0.f};
#pragma unroll
        for (int s = 0; s < 4; ++s) {
            bf16x8 bF = *(const bf16x8*)&swC2[((t*4+s)*64 + lane)*8];
            a = __builtin_amdgcn_mfma_f32_16x16x32_bf16(aF2[s], bF, a, 0, 0, 0);
        }
#pragma unroll
        for (int rr = 0; rr < 4; ++rr) {
            if (vald[rr])
                atomicAdd(&tf[(size_t)dstrow[rr]*128 + t*16 + m], a[rr]);
        }
    }
}

__global__ __launch_bounds__(256) void k_out_old(
    const float* __restrict__ tf, const float* __restrict__ identity,
    const float* __restrict__ g_n, const float* __restrict__ be_n,
    const float* __restrict__ g_m1, const float* __restrict__ be_m1,
    const float* __restrict__ g_m2, const float* __restrict__ be_m2,
    const bf16_t* __restrict__ swM1, const bf16_t* __restrict__ swM2,
    float* __restrict__ out, int Nt)
{
    __shared__ alignas(16) bf16_t sA[4][2048];
    int tid = threadIdx.x, lane = tid & 63, wave = tid >> 6;

    int tb = (blockIdx.x*4 + wave)*16;
    int r = lane >> 2, cb = (lane & 3)*32;
    int grow = tb + r;
    bool rv = grow < Nt;
    const float4* src = (const float4*)(tf + (size_t)(rv ? grow : 0)*128 + cb);
    float vals[32];
    float ls = 0.f, lq = 0.f;
#pragma unroll
    for (int i = 0; i < 8; ++i) {
        float4 v = rv ? src[i] : make_float4(0.f,0.f,0.f,0.f);
        vals[4*i+0]=v.x; vals[4*i+1]=v.y; vals[4*i+2]=v.z; vals[4*i+3]=v.w;
        ls += v.x+v.y+v.z+v.w;
        lq += v.x*v.x+v.y*v.y+v.z*v.z+v.w*v.w;
    }
    ls += __shfl_xor(ls,1); lq += __shfl_xor(lq,1);
    ls += __shfl_xor(ls,2); lq += __shfl_xor(lq,2);
    float mean = ls*(1.f/128.f);
    float inv = rsqrtf(lq*(1.f/128.f) - mean*mean + EPSF);
#pragma unroll
    for (int i = 0; i < 8; ++i) {
        int cc = cb + 4*i;
        float4 ga = *(const float4*)(g_n + cc);
        float4 be = *(const float4*)(be_n + cc);
        float o0 = fmaxf((vals[4*i+0]-mean)*inv*ga.x + be.x, 0.f);
        float o1 = fmaxf((vals[4*i+1]-mean)*inv*ga.y + be.y, 0.f);
        float o2 = fmaxf((vals[4*i+2]-mean)*inv*ga.z + be.z, 0.f);
        float o3 = fmaxf((vals[4*i+3]-mean)*inv*ga.w + be.w, 0.f);
        int s = cc >> 5, q = (cc >> 3) & 3, j = cc & 7;
        bf16x4 pk = { (bf16_t)o0, (bf16_t)o1, (bf16_t)o2, (bf16_t)o3 };
        *(bf16x4*)&sA[wave][(s*64 + q*16 + r)*8 + j] = pk;
    }
    __syncthreads();
    int m = lane & 15, g = lane >> 4;
    bf16x8 aF[4];
#pragma unroll
    for (int s = 0; s < 4; ++s) aF[s] = *(const bf16x8*)&sA[wave][(s*64 + lane)*8];
    floatx4 acc[8];
#pragma unroll
    for (int t = 0; t < 8; ++t) {
        floatx4 a = {0.f,0.f,0.f,0.f};
#pragma unroll
        for (int s = 0; s < 4; ++s) {
            bf16x8 bF = *(const bf16x8*)&swM1[((t*4+s)*64 + lane)*8];
            a = __builtin_amdgcn_mfma_f32_16x16x32_bf16(aF[s], bF, a, 0, 0, 0);
        }
        acc[t] = a;
    }
    gn_rows(acc, lane, g_m1, be_m1, true);
    __syncthreads();
#pragma unroll
    for (int t = 0; t < 8; ++t) {
        int n = t*16 + m;
        int s = n >> 5, q = (n >> 3) & 3, j = n & 7;
#pragma unroll
        for (int rr = 0; rr < 4; ++rr)
            sA[wave][(s*64 + q*16 + (g*4+rr))*8 + j] = (bf16_t)acc[t][rr];
    }
    __syncthreads();
#pragma unroll
    for (int s = 0; s < 4; ++s) aF[s] = *(const bf16x8*)&sA[wave][(s*64 + lane)*8];
#pragma unroll
    for (int t = 0; t < 8; ++t) {
        floatx4 a = {0.f,0.f,0.f,0.f};
#pragma unroll
        for (int s = 0; s < 4; ++s) {
            bf16x8 bF = *(const bf16x8*)&swM2[((t*4+s)*64 + lane)*8];
            a = __builtin_amdgcn_mfma_f32_16x16x32_bf16(aF[s], bF, a, 0, 0, 0);
        }
        acc[t] = a;
    }
    gn_rows(acc, lane, g_m2, be_m2, false);
#pragma unroll
    for (int t = 0; t < 8; ++t) {
        int n = t*16 + m;
#pragma unroll
        for (int rr = 0; rr < 4; ++rr) {
            int row = tb + g*4 + rr;
            if (row < Nt) {
                float v = acc[t][rr] + identity[(size_t)row*128 + n];
                out[(size_t)row*128 + n] = fmaxf(v, 0.f);
            }
        }
    }
}

// ---------------------------------------------------------------------------
extern "C" void kernel_launch(void* const* d_in, const int* in_sizes, int n_in,
                              void* d_out, int out_size, void* d_ws, size_t ws_size,
                              hipStream_t stream)
{
    const float* cfeat  = (const float*)d_in[0];
    const float* tfeat  = (const float*)d_in[1];
    const float* cpose  = (const float*)d_in[2];
    const float* tpose  = (const float*)d_in[3];
    const int*   hi     = (const int*)d_in[4];
    const int*   wi     = (const int*)d_in[5];
    const float* W_in   = (const float*)d_in[6];
    const float* W_rp   = (const float*)d_in[7];
    const float* b_rp   = (const float*)d_in[8];
    const float* W_ctx1 = (const float*)d_in[9];
    const float* g_ctx  = (const float*)d_in[10];
    const float* be_ctx = (const float*)d_in[11];
    const float* W_ctx2 = (const float*)d_in[12];
    const float* g_n    = (const float*)d_in[13];
    const float* be_n   = (const float*)d_in[14];
    const float* W_m1   = (const float*)d_in[15];
    const float* g_m1   = (const float*)d_in[16];
    const float* be_m1  = (const float*)d_in[17];
    const float* W_m2   = (const float*)d_in[18];
    const float* g_m2   = (const float*)d_in[19];
    const float* be_m2  = (const float*)d_in[20];

    int Nt = in_sizes[1] / 128;
    int E  = in_sizes[4];
    float* outp = (float*)d_out;

    // new-path workspace layout
    char* base = (char*)d_ws;
    size_t o = 98304 * sizeof(bf16_t);                 // sw @ 0
    o = (o + 255) & ~(size_t)255;
    size_t o_cnt = o; o += (size_t)Nt * 4;
    o = (o + 255) & ~(size_t)255;
    size_t o_off = o; o += ((size_t)Nt + 1) * 4;
    o = (o + 255) & ~(size_t)255;
    size_t o_cur = o; o += (size_t)Nt * 4;
    o = (o + 255) & ~(size_t)255;
    size_t o_h = o; o += (size_t)E * 128 * sizeof(bf16_t);

    if (ws_size >= o) {
        bf16_t* sw   = (bf16_t*)base;
        int*    cnt  = (int*)(base + o_cnt);
        int*    off  = (int*)(base + o_off);
        int*    cur  = (int*)(base + o_cur);
        bf16_t* hbuf = (bf16_t*)(base + o_h);
        bf16_t* swIn = sw;
        bf16_t* swC1 = sw + 16384;
        bf16_t* swC2 = sw + 49152;
        bf16_t* swM1 = sw + 65536;
        bf16_t* swM2 = sw + 81920;

        hipMemsetAsync(cnt, 0, (size_t)Nt * 4, stream);
        hipMemsetAsync(cur, 0, (size_t)Nt * 4, stream);
        k_prep<<<384, 256, 0, stream>>>(W_in, W_ctx1, W_ctx2, W_m1, W_m2, sw);
        k_count<<<(E + 255) / 256, 256, 0, stream>>>(wi, cnt, E);
        k_scan<<<1, 1024, 0, stream>>>(cnt, off, Nt);
        k_edge3<<<(E + 63) / 64, 256, 0, stream>>>(cfeat, cpose, tpose, hi, wi,
                                                   W_rp, b_rp, g_ctx, be_ctx,
                                                   swC1, off, cur, hbuf, E);
        k_out2<<<(Nt + 63) / 64, 256, 0, stream>>>(tfeat, hbuf, off,
                                                   g_n, be_n, g_m1, be_m1,
                                                   g_m2, be_m2,
                                                   swIn, swC2, swM1, swM2,
                                                   outp, Nt);
    } else {
        // fallback: previous atomic-scatter path
        float*  tf = (float*)d_ws;                                   // [Nt,128] f32
        bf16_t* sw = (bf16_t*)((char*)d_ws + (size_t)Nt * 128 * sizeof(float));
        bf16_t* swIn = sw;
        bf16_t* swC1 = sw + 16384;
        bf16_t* swC2 = sw + 49152;
        bf16_t* swM1 = sw + 65536;
        bf16_t* swM2 = sw + 81920;

        k_prep<<<384, 256, 0, stream>>>(W_in, W_ctx1, W_ctx2, W_m1, W_m2, sw);
        k_gemm_in<<<(Nt + 63) / 64, 256, 0, stream>>>(tfeat, swIn, tf, Nt);
        k_edge_old<<<(E + 63) / 64, 256, 0, stream>>>(cfeat, cpose, tpose, hi, wi,
                                                      W_rp, b_rp, g_ctx, be_ctx,
                                                      swC1, swC2, tf, E);
        k_out_old<<<(Nt + 63) / 64, 256, 0, stream>>>(tf, tfeat, g_n, be_n,
                                                      g_m1, be_m1, g_m2, be_m2,
                                                      swM1, swM2, outp, Nt);
    }
}